// Round 14
// baseline (384.830 us; speedup 1.0000x reference)
//
#include <hip/hip_runtime.h>
#include <hip/hip_bf16.h>

#define NE 100000
#define NR 500
#define DD 128
#define NT 250000
#define NEV 500000             // 2*NT events
#define RELOFF 12800000        // NE*DD
#define TWO_NF 500000.0f
#define NTF 250000.0f
#define TBH 2048
#define NBH ((NT + TBH - 1)/TBH)   // 123
#define NBS ((NE + 1023)/1024)     // 98

typedef __attribute__((ext_vector_type(8))) short short8;
typedef __attribute__((ext_vector_type(4))) float f32x4;

__device__ __forceinline__ float bf2f(unsigned short u){
  unsigned int x = ((unsigned int)u) << 16;
  return __uint_as_float(x);
}
__device__ __forceinline__ float bf2f_lo(unsigned int u){ return __uint_as_float(u << 16); }
__device__ __forceinline__ float bf2f_hi(unsigned int u){ return __uint_as_float(u & 0xFFFF0000u); }
__device__ __forceinline__ unsigned short f2bf(float f){
  __hip_bfloat16 h = __float2bfloat16(f);
  return *reinterpret_cast<unsigned short*>(&h);
}
__device__ __forceinline__ void atomAddF(float* p, float v){ unsafeAtomicAdd(p, v); }
__device__ __forceinline__ float wredsum(float x){
  x += __shfl_xor(x, 1, 64);  x += __shfl_xor(x, 2, 64);  x += __shfl_xor(x, 4, 64);
  x += __shfl_xor(x, 8, 64);  x += __shfl_xor(x, 16, 64); x += __shfl_xor(x, 32, 64);
  return x;
}
__device__ __forceinline__ int wredsumi(int x){
  x += __shfl_xor(x, 1, 64);  x += __shfl_xor(x, 2, 64);  x += __shfl_xor(x, 4, 64);
  x += __shfl_xor(x, 8, 64);  x += __shfl_xor(x, 16, 64); x += __shfl_xor(x, 32, 64);
  return x;
}

// ---------------- K1: per-block rel histogram + entity counts ----------------
__global__ __launch_bounds__(256) void k_hist(const int* __restrict__ trip,
                                              int* __restrict__ cnt, int* __restrict__ gHist){
  __shared__ int h[NR];
  int t = threadIdx.x;
  for (int r = t; r < NR; r += 256) h[r] = 0;
  __syncthreads();
  int b0 = blockIdx.x*TBH, b1 = min(b0+TBH, NT);
  for (int i = b0 + t; i < b1; i += 256){
    int t0 = trip[3*i], t1 = trip[3*i+1], t2 = trip[3*i+2];
    atomicAdd(&cnt[t0], 1);
    atomicAdd(&cnt[t1], 1);
    atomicAdd(&h[t2], 1);
  }
  __syncthreads();
  for (int r = t; r < NR; r += 256) gHist[blockIdx.x*NR + r] = h[r];
}

// ---------------- K1b: column-scan hists -> per-(block,rel) base, cntR, offR ----------------
__global__ __launch_bounds__(512) void k_histscan(const int* __restrict__ gHist,
                                                  int* __restrict__ base, int* __restrict__ cntR,
                                                  int* __restrict__ offR){
  __shared__ int sm[512];
  int r = threadIdx.x;
  int s = 0;
  if (r < NR){
    for (int b = 0; b < NBH; ++b){ base[b*NR + r] = s; s += gHist[b*NR + r]; }
    cntR[r] = s;
  }
  sm[r] = (r < NR) ? s : 0;
  __syncthreads();
  for (int st = 1; st < 512; st <<= 1){
    int x = (r >= st) ? sm[r-st] : 0;
    __syncthreads();
    sm[r] += x;
    __syncthreads();
  }
  if (r < NR){
    int off = sm[r] - s;               // exclusive
    offR[r] = off;
    for (int b = 0; b < NBH; ++b) base[b*NR + r] += off;
  }
  if (r == 0) offR[NR] = NT;
}

// ---------------- device-wide entity scan: phase 1 (block-local) ----------------
__global__ __launch_bounds__(1024) void k_scan1(const int* __restrict__ cnt,
                                                int* __restrict__ off, int* __restrict__ bsum){
  __shared__ int wsum[16];
  int t = threadIdx.x, lane = t & 63, w = t >> 6;
  int i = blockIdx.x*1024 + t;
  int v = (i < NE) ? cnt[i] : 0;
  int x = v;
  #pragma unroll
  for (int s = 1; s < 64; s <<= 1){ int y = __shfl_up(x, s, 64); if (lane >= s) x += y; }
  if (lane == 63) wsum[w] = x;
  __syncthreads();
  if (w == 0 && lane < 16){
    int xs = wsum[lane];
    #pragma unroll
    for (int s = 1; s < 16; s <<= 1){ int y = __shfl_up(xs, s, 16); if ((lane & 15) >= s) xs += y; }
    wsum[lane] = xs;
  }
  __syncthreads();
  int wprev = (w == 0) ? 0 : wsum[w-1];
  int incl = wprev + x;
  if (i < NE) off[i] = incl - v;          // block-local exclusive
  if (t == 1023) bsum[blockIdx.x] = incl; // block total
}

// ---------------- scan phases 2+3 fused ----------------
__global__ __launch_bounds__(1024) void k_scan23(const int* __restrict__ bsum,
                                                 int* __restrict__ off, int* __restrict__ cur){
  __shared__ int basesh;
  int t = threadIdx.x;
  if (t < 64){
    int acc = 0;
    for (int b = t; b < blockIdx.x; b += 64) acc += bsum[b];
    acc = wredsumi(acc);
    if (t == 0) basesh = acc;
  }
  __syncthreads();
  int base = basesh;
  int i = blockIdx.x*1024 + t;
  if (i < NE){
    int o = off[i] + base;
    off[i] = o;
    cur[i] = o;
  }
  if (blockIdx.x == NBS-1 && t == 0) off[NE] = base + bsum[NBS-1];
}

// ---------------- scatter entity events (global cursors, nt stores) ----------------
__global__ void k_scat_ent(const int* __restrict__ trip, int* __restrict__ curE,
                           unsigned long long* __restrict__ evE){
  int i = blockIdx.x*blockDim.x + threadIdx.x;
  if (i < NT){
    int t0 = trip[3*i+0], t1 = trip[3*i+1], t2 = trip[3*i+2];
    int p0 = atomicAdd(&curE[t0], 1);
    unsigned long long e0 = (unsigned)t0 |
      ((unsigned long long)(((unsigned)t1 << 10) | ((unsigned)t2 << 1)) << 32);
    __builtin_nontemporal_store(e0, &evE[p0]);
    int p1 = atomicAdd(&curE[t1], 1);
    unsigned long long e1 = (unsigned)t1 |
      ((unsigned long long)(((unsigned)t0 << 10) | ((unsigned)t2 << 1) | 1u) << 32);
    __builtin_nontemporal_store(e1, &evE[p1]);
  }
}

// ---------------- scatter rel events (LDS cursors, deterministic bases) ----------------
__global__ __launch_bounds__(256) void k_scat_rel(const int* __restrict__ trip,
                                                  const int* __restrict__ base,
                                                  unsigned long long* __restrict__ evR){
  __shared__ int cur[NR];
  int t = threadIdx.x;
  for (int r = t; r < NR; r += 256) cur[r] = base[blockIdx.x*NR + r];
  __syncthreads();
  int b0 = blockIdx.x*TBH, b1 = min(b0+TBH, NT);
  for (int i = b0 + t; i < b1; i += 256){
    int t0 = trip[3*i], t1 = trip[3*i+1], t2 = trip[3*i+2];
    int p = atomicAdd(&cur[t2], 1);
    unsigned long long e = (unsigned)t0 | ((unsigned long long)(unsigned)t1 << 32);
    __builtin_nontemporal_store(e, &evR[p]);
  }
}

// ---------------- K2: entity column stats + fused X->bf16 convert ----------------
__global__ __launch_bounds__(256) void k_entstats(const float* __restrict__ ent, const int* __restrict__ cnt,
                                                  float* __restrict__ S, float* __restrict__ Q,
                                                  unsigned short* __restrict__ Xbf){
  int j = threadIdx.x & 127;
  int half = threadIdx.x >> 7;
  int r0 = blockIdx.x*128 + half;
  int r1 = min(blockIdx.x*128 + 128, NE);
  float s = 0.f, q = 0.f;
  for (int r = r0; r < r1; r += 2){
    float x = ent[(size_t)r*DD + j];
    Xbf[(size_t)r*DD + j] = f2bf(x);
    int w = cnt[r];
    if (w){
      float wf = (float)w;
      s += wf*x; q += wf*x*x;
    }
  }
  __shared__ float ss[256], qq[256];
  ss[threadIdx.x] = s; qq[threadIdx.x] = q; __syncthreads();
  if (half == 0){
    atomAddF(&S[j], ss[j] + ss[j+128]);
    atomAddF(&Q[j], qq[j] + qq[j+128]);
  }
}

// ---------------- K3: BN0 fold + rel variance ----------------
__global__ void k_alpha(const float* __restrict__ rel, const int* __restrict__ cntR,
                        const float* __restrict__ S, const float* __restrict__ Q,
                        const float* __restrict__ bn0g, const float* __restrict__ bn0b,
                        float* __restrict__ alpha0, float* __restrict__ alpha1, float* __restrict__ alpha2,
                        float* __restrict__ beta0, float* __restrict__ beta1){
  int j = threadIdx.x;
  float qr = 0.f;
  for (int k = 0; k < NR; ++k){
    float w = (float)cntR[k];
    float x = rel[k*DD + j];
    qr += w*x*x;
  }
  float mean = S[j] / TWO_NF;
  float var  = Q[j] / TWO_NF - mean*mean;
  float inv  = rsqrtf(var + 1e-5f);
  float a0 = inv * bn0g[j];
  float a1 = inv * bn0g[128+j];
  alpha0[j] = a0; alpha1[j] = a1;
  beta0[j] = bn0b[j]     - mean*a0;
  beta1[j] = bn0b[128+j] - mean*a1;
  float varR = qr / NTF;
  alpha2[j] = rsqrtf(varR + 1e-5f) * bn0g[256+j];
}

// ---------------- K_fold: bias (blocks 0..127) | V+Vbf (128..627) | Wt2 (628..883) ----------------
__global__ __launch_bounds__(128) void k_fold(const float* __restrict__ aw, const float* __restrict__ ab,
                        const float* __restrict__ bn0b, const float* __restrict__ rel,
                        const float* __restrict__ alpha0, const float* __restrict__ alpha1,
                        const float* __restrict__ alpha2,
                        const float* __restrict__ beta0, const float* __restrict__ beta1,
                        float* __restrict__ bias, float* __restrict__ V,
                        unsigned short* __restrict__ Vbf, unsigned short* __restrict__ Wt2){
  __shared__ float sm[128];
  int b = blockIdx.x, j = threadIdx.x;
  if (b < 128){
    int o = b;
    const float* r = aw + (size_t)o*384;
    float p = r[j]*beta0[j] + r[128+j]*beta1[j] + r[256+j]*bn0b[256+j];
    sm[j] = p; __syncthreads();
    for (int s = 64; s > 0; s >>= 1){ if (j < s) sm[j] += sm[j+s]; __syncthreads(); }
    if (j == 0) bias[o] = ab[o] + sm[0];
  } else if (b < 628){
    int k = b - 128;
    sm[j] = rel[k*DD + j] * alpha2[j];
    __syncthreads();
    float acc = 0.f;
    #pragma unroll 8
    for (int q = 0; q < 128; ++q) acc += aw[(size_t)j*384 + 256 + q] * sm[q];
    V[k*DD + j] = acc;
    Vbf[k*DD + j] = f2bf(acc);
  } else {
    int o = b - 628;           // 0..255
    int k = j;                 // 0..127
    float w;
    if (o < 128) w = aw[(size_t)o*384 + k] * alpha0[k];
    else         w = aw[(size_t)(o-128)*384 + 128 + k] * alpha1[k];
    Wt2[(size_t)o*128 + k] = f2bf(w);
  }
}

// ---------------- K6: U table via MFMA — wave owns 4 output tiles, B in registers ----------------
__global__ __launch_bounds__(256) void k_u2(const unsigned short* __restrict__ Xbf,
                                            const unsigned short* __restrict__ Wt2,
                                            unsigned short* __restrict__ Uo){
  int tid = threadIdx.x;
  int w = tid >> 6, l = tid & 63;
  int col = l & 15, grp = l >> 4, kof = grp*8;
  int e0 = blockIdx.x*64;                    // 1563 blocks * 64 = 100032
  int ot0 = w*4;

  const unsigned short* wb0 = Wt2 + (size_t)((ot0+0)*16 + col)*128 + kof;
  const unsigned short* wb1 = Wt2 + (size_t)((ot0+1)*16 + col)*128 + kof;
  const unsigned short* wb2 = Wt2 + (size_t)((ot0+2)*16 + col)*128 + kof;
  const unsigned short* wb3 = Wt2 + (size_t)((ot0+3)*16 + col)*128 + kof;
  short8 b00 = *(const short8*)(wb0);
  short8 b01 = *(const short8*)(wb0+32);
  short8 b02 = *(const short8*)(wb0+64);
  short8 b03 = *(const short8*)(wb0+96);
  short8 b10 = *(const short8*)(wb1);
  short8 b11 = *(const short8*)(wb1+32);
  short8 b12 = *(const short8*)(wb1+64);
  short8 b13 = *(const short8*)(wb1+96);
  short8 b20 = *(const short8*)(wb2);
  short8 b21 = *(const short8*)(wb2+32);
  short8 b22 = *(const short8*)(wb2+64);
  short8 b23 = *(const short8*)(wb2+96);
  short8 b30 = *(const short8*)(wb3);
  short8 b31 = *(const short8*)(wb3+32);
  short8 b32 = *(const short8*)(wb3+64);
  short8 b33 = *(const short8*)(wb3+96);

  #pragma unroll
  for (int et = 0; et < 4; ++et){
    int ebase = e0 + et*16;
    int e = min(ebase + col, NE-1);
    const unsigned short* xrow = Xbf + (size_t)e*DD;
    short8 a0 = *(const short8*)(xrow + kof);
    short8 a1 = *(const short8*)(xrow + 32 + kof);
    short8 a2 = *(const short8*)(xrow + 64 + kof);
    short8 a3 = *(const short8*)(xrow + 96 + kof);
    f32x4 c0 = (f32x4){0.f,0.f,0.f,0.f};
    f32x4 c1 = (f32x4){0.f,0.f,0.f,0.f};
    f32x4 c2 = (f32x4){0.f,0.f,0.f,0.f};
    f32x4 c3 = (f32x4){0.f,0.f,0.f,0.f};
    c0 = __builtin_amdgcn_mfma_f32_16x16x32_bf16(a0, b00, c0, 0, 0, 0);
    c1 = __builtin_amdgcn_mfma_f32_16x16x32_bf16(a0, b10, c1, 0, 0, 0);
    c2 = __builtin_amdgcn_mfma_f32_16x16x32_bf16(a0, b20, c2, 0, 0, 0);
    c3 = __builtin_amdgcn_mfma_f32_16x16x32_bf16(a0, b30, c3, 0, 0, 0);
    c0 = __builtin_amdgcn_mfma_f32_16x16x32_bf16(a1, b01, c0, 0, 0, 0);
    c1 = __builtin_amdgcn_mfma_f32_16x16x32_bf16(a1, b11, c1, 0, 0, 0);
    c2 = __builtin_amdgcn_mfma_f32_16x16x32_bf16(a1, b21, c2, 0, 0, 0);
    c3 = __builtin_amdgcn_mfma_f32_16x16x32_bf16(a1, b31, c3, 0, 0, 0);
    c0 = __builtin_amdgcn_mfma_f32_16x16x32_bf16(a2, b02, c0, 0, 0, 0);
    c1 = __builtin_amdgcn_mfma_f32_16x16x32_bf16(a2, b12, c1, 0, 0, 0);
    c2 = __builtin_amdgcn_mfma_f32_16x16x32_bf16(a2, b22, c2, 0, 0, 0);
    c3 = __builtin_amdgcn_mfma_f32_16x16x32_bf16(a2, b32, c3, 0, 0, 0);
    c0 = __builtin_amdgcn_mfma_f32_16x16x32_bf16(a3, b03, c0, 0, 0, 0);
    c1 = __builtin_amdgcn_mfma_f32_16x16x32_bf16(a3, b13, c1, 0, 0, 0);
    c2 = __builtin_amdgcn_mfma_f32_16x16x32_bf16(a3, b23, c2, 0, 0, 0);
    c3 = __builtin_amdgcn_mfma_f32_16x16x32_bf16(a3, b33, c3, 0, 0, 0);
    #pragma unroll
    for (int r = 0; r < 4; ++r){
      int row = ebase + 4*grp + r;
      if (row < NE){
        size_t rb = (size_t)row*256 + col;
        Uo[rb + (ot0+0)*16] = f2bf(c0[r]);
        Uo[rb + (ot0+1)*16] = f2bf(c1[r]);
        Uo[rb + (ot0+2)*16] = f2bf(c2[r]);
        Uo[rb + (ot0+3)*16] = f2bf(c3[r]);
      }
    }
  }
}

// ---------------- K7: BN1 column stats over CSR events (unroll x8, named) ----------------
__global__ __launch_bounds__(256) void k_c1b(const uint2* __restrict__ evE,
                   const unsigned short* __restrict__ U, const unsigned short* __restrict__ Vbf,
                   const float* __restrict__ bias,
                   float* __restrict__ colsum, float* __restrict__ colsumsq){
  int lane = threadIdx.x & 63;
  int w = threadIdx.x >> 6;
  int wv = blockIdx.x*4 + w;
  int nwv = gridDim.x*4;
  int per = (NEV + nwv - 1) / nwv;
  int st = wv*per, en = min(st + per, NEV);
  int c0 = 2*lane, c1 = c0+1;
  float b0 = bias[c0], b1 = bias[c1];
  const ushort2* Ub = (const ushort2*)U;
  const ushort2* Vb = (const ushort2*)Vbf;
  float s0=0.f, s1=0.f, q0=0.f, q1=0.f;
  for (int bs = st; bs < en; bs += 64){
    int n = min(64, en - bs);
    uint2 ev = (bs + lane < en) ? evE[bs + lane] : make_uint2(0u, 0u);
    int j = 0;
    for (; j + 8 <= n; j += 8){
      unsigned owA = __shfl(ev.x, j,   64), pkA = __shfl(ev.y, j,   64);
      unsigned owB = __shfl(ev.x, j+1, 64), pkB = __shfl(ev.y, j+1, 64);
      unsigned owC = __shfl(ev.x, j+2, 64), pkC = __shfl(ev.y, j+2, 64);
      unsigned owD = __shfl(ev.x, j+3, 64), pkD = __shfl(ev.y, j+3, 64);
      unsigned owE = __shfl(ev.x, j+4, 64), pkE = __shfl(ev.y, j+4, 64);
      unsigned owF = __shfl(ev.x, j+5, 64), pkF = __shfl(ev.y, j+5, 64);
      unsigned owG = __shfl(ev.x, j+6, 64), pkG = __shfl(ev.y, j+6, 64);
      unsigned owH = __shfl(ev.x, j+7, 64), pkH = __shfl(ev.y, j+7, 64);
      ushort2 aA = Ub[(size_t)owA*128 + lane];
      ushort2 gA = Ub[(size_t)(pkA >> 10)*128 + 64 + lane];
      ushort2 vA = Vb[((pkA >> 1) & 0x1FF)*64 + lane];
      ushort2 aB = Ub[(size_t)owB*128 + lane];
      ushort2 gB = Ub[(size_t)(pkB >> 10)*128 + 64 + lane];
      ushort2 vB = Vb[((pkB >> 1) & 0x1FF)*64 + lane];
      ushort2 aC = Ub[(size_t)owC*128 + lane];
      ushort2 gC = Ub[(size_t)(pkC >> 10)*128 + 64 + lane];
      ushort2 vC = Vb[((pkC >> 1) & 0x1FF)*64 + lane];
      ushort2 aD = Ub[(size_t)owD*128 + lane];
      ushort2 gD = Ub[(size_t)(pkD >> 10)*128 + 64 + lane];
      ushort2 vD = Vb[((pkD >> 1) & 0x1FF)*64 + lane];
      ushort2 aE = Ub[(size_t)owE*128 + lane];
      ushort2 gE = Ub[(size_t)(pkE >> 10)*128 + 64 + lane];
      ushort2 vE = Vb[((pkE >> 1) & 0x1FF)*64 + lane];
      ushort2 aF = Ub[(size_t)owF*128 + lane];
      ushort2 gF = Ub[(size_t)(pkF >> 10)*128 + 64 + lane];
      ushort2 vF = Vb[((pkF >> 1) & 0x1FF)*64 + lane];
      ushort2 aG = Ub[(size_t)owG*128 + lane];
      ushort2 gG = Ub[(size_t)(pkG >> 10)*128 + 64 + lane];
      ushort2 vG = Vb[((pkG >> 1) & 0x1FF)*64 + lane];
      ushort2 aH = Ub[(size_t)owH*128 + lane];
      ushort2 gH = Ub[(size_t)(pkH >> 10)*128 + 64 + lane];
      ushort2 vH = Vb[((pkH >> 1) & 0x1FF)*64 + lane];
      float sgA = (pkA & 1) ? -1.f : 1.f;
      float sgB = (pkB & 1) ? -1.f : 1.f;
      float sgC = (pkC & 1) ? -1.f : 1.f;
      float sgD = (pkD & 1) ? -1.f : 1.f;
      float sgE = (pkE & 1) ? -1.f : 1.f;
      float sgF = (pkF & 1) ? -1.f : 1.f;
      float sgG = (pkG & 1) ? -1.f : 1.f;
      float sgH = (pkH & 1) ? -1.f : 1.f;
      float yA0 = bf2f(aA.x) + bf2f(gA.x) + sgA*bf2f(vA.x) + b0;
      float yA1 = bf2f(aA.y) + bf2f(gA.y) + sgA*bf2f(vA.y) + b1;
      float yB0 = bf2f(aB.x) + bf2f(gB.x) + sgB*bf2f(vB.x) + b0;
      float yB1 = bf2f(aB.y) + bf2f(gB.y) + sgB*bf2f(vB.y) + b1;
      float yC0 = bf2f(aC.x) + bf2f(gC.x) + sgC*bf2f(vC.x) + b0;
      float yC1 = bf2f(aC.y) + bf2f(gC.y) + sgC*bf2f(vC.y) + b1;
      float yD0 = bf2f(aD.x) + bf2f(gD.x) + sgD*bf2f(vD.x) + b0;
      float yD1 = bf2f(aD.y) + bf2f(gD.y) + sgD*bf2f(vD.y) + b1;
      float yE0 = bf2f(aE.x) + bf2f(gE.x) + sgE*bf2f(vE.x) + b0;
      float yE1 = bf2f(aE.y) + bf2f(gE.y) + sgE*bf2f(vE.y) + b1;
      float yF0 = bf2f(aF.x) + bf2f(gF.x) + sgF*bf2f(vF.x) + b0;
      float yF1 = bf2f(aF.y) + bf2f(gF.y) + sgF*bf2f(vF.y) + b1;
      float yG0 = bf2f(aG.x) + bf2f(gG.x) + sgG*bf2f(vG.x) + b0;
      float yG1 = bf2f(aG.y) + bf2f(gG.y) + sgG*bf2f(vG.y) + b1;
      float yH0 = bf2f(aH.x) + bf2f(gH.x) + sgH*bf2f(vH.x) + b0;
      float yH1 = bf2f(aH.y) + bf2f(gH.y) + sgH*bf2f(vH.y) + b1;
      s0 += (yA0 + yB0) + (yC0 + yD0) + (yE0 + yF0) + (yG0 + yH0);
      s1 += (yA1 + yB1) + (yC1 + yD1) + (yE1 + yF1) + (yG1 + yH1);
      q0 += (yA0*yA0 + yB0*yB0) + (yC0*yC0 + yD0*yD0) + (yE0*yE0 + yF0*yF0) + (yG0*yG0 + yH0*yH0);
      q1 += (yA1*yA1 + yB1*yB1) + (yC1*yC1 + yD1*yD1) + (yE1*yE1 + yF1*yF1) + (yG1*yG1 + yH1*yH1);
    }
    for (; j < n; ++j){
      unsigned owA = __shfl(ev.x, j, 64), pkA = __shfl(ev.y, j, 64);
      ushort2 aA = Ub[(size_t)owA*128 + lane];
      ushort2 gA = Ub[(size_t)(pkA >> 10)*128 + 64 + lane];
      ushort2 vA = Vb[((pkA >> 1) & 0x1FF)*64 + lane];
      float sgA = (pkA & 1) ? -1.f : 1.f;
      float yA0 = bf2f(aA.x) + bf2f(gA.x) + sgA*bf2f(vA.x) + b0;
      float yA1 = bf2f(aA.y) + bf2f(gA.y) + sgA*bf2f(vA.y) + b1;
      s0 += yA0;  q0 += yA0*yA0;
      s1 += yA1;  q1 += yA1*yA1;
    }
  }
  __shared__ float sred[4][128], qred[4][128];
  sred[w][c0] = s0; sred[w][c1] = s1;
  qred[w][c0] = q0; qred[w][c1] = q1;
  __syncthreads();
  int t = threadIdx.x;
  if (t < 128){
    atomAddF(&colsum[t],   sred[0][t] + sred[1][t] + sred[2][t] + sred[3][t]);
    atomAddF(&colsumsq[t], qred[0][t] + qred[1][t] + qred[2][t] + qred[3][t]);
  }
}

// ---------------- K8: BN1 fold + a2 fold + pbsb ----------------
__global__ void k_bn1fin(const float* __restrict__ colsum, const float* __restrict__ colsumsq,
                         const float* __restrict__ bn1g, const float* __restrict__ bn1b,
                         const float* __restrict__ a2w, const float* __restrict__ a2b,
                         const float* __restrict__ biasv,
                         float* __restrict__ A1, float* __restrict__ B1,
                         float* __restrict__ a2A, float* __restrict__ sbase){
  int j = threadIdx.x;
  float mean = colsum[j] / TWO_NF;
  float var  = colsumsq[j] / TWO_NF - mean*mean;
  float A = rsqrtf(var + 1e-5f) * bn1g[j];
  float B = bn1b[j] - mean*A;
  A1[j] = A; B1[j] = B;
  float w2 = a2w[j];
  float aA = w2*A;
  a2A[j] = aA;
  __shared__ float sm[128], sm2[128];
  sm[j] = w2*B; sm2[j] = biasv[j]*aA;
  __syncthreads();
  for (int s = 64; s > 0; s >>= 1){
    if (j < s){ sm[j] += sm[j+s]; sm2[j] += sm2[j+s]; }
    __syncthreads();
  }
  if (j == 0){
    float sb = a2b[0] + sm[0];
    sbase[0] = sb;
    sbase[1] = sb + sm2[0];   // pbsb = dot(bias,a2A) + sbase
  }
}

// ---------------- K_sigrho: sigma (blocks 0..24999) | rho (25000..25124) ----------------
__global__ __launch_bounds__(256) void k_sigrho(const unsigned short* __restrict__ U,
                                                const float* __restrict__ V,
                                                const float* __restrict__ a2A,
                                                float* __restrict__ sig, float* __restrict__ rho){
  int lane = threadIdx.x & 63;
  if (blockIdx.x < NE/4){
    int e = blockIdx.x*4 + (threadIdx.x>>6);
    const uint2* Ur = (const uint2*)U;
    uint2 r = Ur[(size_t)e*64 + lane];
    int c = (lane & 31)*4;
    float4 w = *(const float4*)&a2A[c];
    float p = bf2f_lo(r.x)*w.x + bf2f_hi(r.x)*w.y + bf2f_lo(r.y)*w.z + bf2f_hi(r.y)*w.w;
    p += __shfl_xor(p, 1, 64); p += __shfl_xor(p, 2, 64); p += __shfl_xor(p, 4, 64);
    p += __shfl_xor(p, 8, 64); p += __shfl_xor(p, 16, 64);
    if ((lane & 31) == 0) sig[2*e + (lane >> 5)] = p;
  } else {
    int k = (blockIdx.x - NE/4)*4 + (threadIdx.x>>6);
    if (k >= NR) return;
    const float2* Vp = (const float2*)V;
    float2 v = Vp[(size_t)k*64 + lane];
    int c0 = 2*lane;
    float p = v.x*a2A[c0] + v.y*a2A[c0+1];
    p = wredsum(p);
    if (lane == 0) rho[k] = p;
  }
}

// ---------------- K9: entity gather (unroll x4, bf16 V) ----------------
__global__ __launch_bounds__(256) void k_gent(const uint2* __restrict__ evE, const int* __restrict__ offE,
                   const unsigned short* __restrict__ U, const unsigned short* __restrict__ Vbf,
                   const float* __restrict__ sig, const float* __restrict__ rho,
                   const float* __restrict__ bias,
                   const float* __restrict__ A1, const float* __restrict__ B1,
                   const float* __restrict__ sbase,
                   float* __restrict__ out){
  int lane = threadIdx.x & 63;
  int e = blockIdx.x*4 + (threadIdx.x>>6);
  if (e >= NE) return;
  int c0 = 2*lane, c1 = c0+1;
  const ushort2* Ub = (const ushort2*)U;
  const ushort2* Vb = (const ushort2*)Vbf;
  ushort2 u0 = Ub[(size_t)e*128 + lane];
  float base0 = bf2f(u0.x) + bias[c0], base1 = bf2f(u0.y) + bias[c1];
  float pb  = sbase[1];
  float s0e = sig[2*e];
  float accU0=0.f, accU1=0.f, accV0=0.f, accV1=0.f, sep=0.f;
  int p0 = offE[e], p1 = offE[e+1];
  for (int bs = p0; bs < p1; bs += 64){
    int n = min(64, p1 - bs);
    unsigned ev = 0u; float ebl = 0.f;
    if (bs + lane < p1){
      ev = evE[bs + lane].y;
      int oth = ev >> 10, rl = (ev >> 1) & 0x1FF;
      float sg = (ev & 1) ? -1.f : 1.f;
      float s = s0e + sig[2*oth + 1] + sg*rho[rl] + pb;
      float bb = (s >= 0.f) ? -s : -0.01f*s;
      ebl = expf(bb);
    }
    sep += ebl;
    int j = 0;
    for (; j + 4 <= n; j += 4){
      unsigned e0 = __shfl(ev, j, 64);
      unsigned e1 = __shfl(ev, j+1, 64);
      unsigned e2 = __shfl(ev, j+2, 64);
      unsigned e3 = __shfl(ev, j+3, 64);
      float eb0 = __shfl(ebl, j, 64);
      float eb1 = __shfl(ebl, j+1, 64);
      float eb2 = __shfl(ebl, j+2, 64);
      float eb3 = __shfl(ebl, j+3, 64);
      ushort2 g0 = Ub[(size_t)(e0 >> 10)*128 + 64 + lane];
      ushort2 g1 = Ub[(size_t)(e1 >> 10)*128 + 64 + lane];
      ushort2 g2 = Ub[(size_t)(e2 >> 10)*128 + 64 + lane];
      ushort2 g3 = Ub[(size_t)(e3 >> 10)*128 + 64 + lane];
      ushort2 v0 = Vb[((e0 >> 1) & 0x1FF)*64 + lane];
      ushort2 v1 = Vb[((e1 >> 1) & 0x1FF)*64 + lane];
      ushort2 v2 = Vb[((e2 >> 1) & 0x1FF)*64 + lane];
      ushort2 v3 = Vb[((e3 >> 1) & 0x1FF)*64 + lane];
      float w0 = (e0 & 1) ? -eb0 : eb0;
      float w1 = (e1 & 1) ? -eb1 : eb1;
      float w2 = (e2 & 1) ? -eb2 : eb2;
      float w3 = (e3 & 1) ? -eb3 : eb3;
      accU0 += eb0*bf2f(g0.x); accU1 += eb0*bf2f(g0.y);
      accV0 += w0*bf2f(v0.x);  accV1 += w0*bf2f(v0.y);
      accU0 += eb1*bf2f(g1.x); accU1 += eb1*bf2f(g1.y);
      accV0 += w1*bf2f(v1.x);  accV1 += w1*bf2f(v1.y);
      accU0 += eb2*bf2f(g2.x); accU1 += eb2*bf2f(g2.y);
      accV0 += w2*bf2f(v2.x);  accV1 += w2*bf2f(v2.y);
      accU0 += eb3*bf2f(g3.x); accU1 += eb3*bf2f(g3.y);
      accV0 += w3*bf2f(v3.x);  accV1 += w3*bf2f(v3.y);
    }
    for (; j < n; ++j){
      unsigned e0 = __shfl(ev, j, 64);
      float eb0 = __shfl(ebl, j, 64);
      ushort2 g0 = Ub[(size_t)(e0 >> 10)*128 + 64 + lane];
      ushort2 v0 = Vb[((e0 >> 1) & 0x1FF)*64 + lane];
      float w0 = (e0 & 1) ? -eb0 : eb0;
      accU0 += eb0*bf2f(g0.x); accU1 += eb0*bf2f(g0.y);
      accV0 += w0*bf2f(v0.x);  accV1 += w0*bf2f(v0.y);
    }
  }
  float se = wredsum(sep);
  float sY0 = se*base0 + accU0 + accV0;
  float sY1 = se*base1 + accU1 + accV1;
  float hs0 = A1[c0]*sY0 + B1[c0]*se;
  float hs1 = A1[c1]*sY1 + B1[c1]*se;
  float d = (se == 0.f) ? 1e-12f : se;
  out[(size_t)e*DD + c0] = hs0/d;
  out[(size_t)e*DD + c1] = hs1/d;
}

// ---------------- K10: relation gather — one block (16 waves) per rel, direct write ----------------
__global__ __launch_bounds__(1024) void k_grel2(const uint2* __restrict__ evR, const int* __restrict__ offR,
                   const unsigned short* __restrict__ U, const float* __restrict__ V,
                   const float* __restrict__ sig, const float* __restrict__ rho,
                   const float* __restrict__ bias,
                   const float* __restrict__ A1, const float* __restrict__ B1,
                   const float* __restrict__ sbase, const int* __restrict__ cntR,
                   float* __restrict__ out){
  __shared__ float rA[16][64], rB[16][64], sepw[16];
  int lane = threadIdx.x & 63;
  int w = threadIdx.x >> 6;       // 0..15
  int k = blockIdx.x;
  int c0 = 2*lane, c1 = c0+1;
  const ushort2* Ub = (const ushort2*)U;
  const float2*  Vp = (const float2*)V;
  float2 v = Vp[(size_t)k*64 + lane];
  float vb0 = v.x + bias[c0], vb1 = v.y + bias[c1];
  float rpb = rho[k] + sbase[1];
  float accY0=0.f, accY1=0.f, sep=0.f;
  int p0 = offR[k], p1 = offR[k+1];
  for (int bs = p0 + w*64; bs < p1; bs += 16*64){
    int n = min(64, p1 - bs);
    uint2 ev = make_uint2(0u, 0u); float ebl = 0.f;
    if (bs + lane < p1){
      ev = evR[bs + lane];
      float s = sig[2*ev.x] + sig[2*ev.y + 1] + rpb;
      float bb = (s >= 0.f) ? -s : -0.01f*s;
      ebl = expf(bb);
    }
    sep += ebl;
    int j = 0;
    for (; j + 2 <= n; j += 2){
      unsigned a0 = __shfl(ev.x, j, 64),   d0 = __shfl(ev.y, j, 64);
      unsigned a1 = __shfl(ev.x, j+1, 64), d1 = __shfl(ev.y, j+1, 64);
      float eb0 = __shfl(ebl, j, 64);
      float eb1 = __shfl(ebl, j+1, 64);
      ushort2 ua0 = Ub[(size_t)a0*128 + lane];
      ushort2 ud0 = Ub[(size_t)d0*128 + 64 + lane];
      ushort2 ua1 = Ub[(size_t)a1*128 + lane];
      ushort2 ud1 = Ub[(size_t)d1*128 + 64 + lane];
      accY0 += eb0*(bf2f(ua0.x) + bf2f(ud0.x));
      accY1 += eb0*(bf2f(ua0.y) + bf2f(ud0.y));
      accY0 += eb1*(bf2f(ua1.x) + bf2f(ud1.x));
      accY1 += eb1*(bf2f(ua1.y) + bf2f(ud1.y));
    }
    for (; j < n; ++j){
      unsigned a0 = __shfl(ev.x, j, 64), d0 = __shfl(ev.y, j, 64);
      float eb0 = __shfl(ebl, j, 64);
      ushort2 ua0 = Ub[(size_t)a0*128 + lane];
      ushort2 ud0 = Ub[(size_t)d0*128 + 64 + lane];
      accY0 += eb0*(bf2f(ua0.x) + bf2f(ud0.x));
      accY1 += eb0*(bf2f(ua0.y) + bf2f(ud0.y));
    }
  }
  float se_w = wredsum(sep);
  rA[w][lane] = accY0;
  rB[w][lane] = accY1;
  if (lane == 0) sepw[w] = se_w;
  __syncthreads();
  if (threadIdx.x < 64){
    int l = threadIdx.x;
    float sY0 = 0.f, sY1 = 0.f, se = 0.f;
    #pragma unroll
    for (int ww = 0; ww < 16; ++ww){ sY0 += rA[ww][l]; sY1 += rB[ww][l]; se += sepw[ww]; }
    sY0 += se*vb0;
    sY1 += se*vb1;
    float r0 = A1[c0]*sY0 + B1[c0]*se;
    float r1 = A1[c1]*sY1 + B1[c1]*se;
    float cdiv = fmaxf((float)cntR[k], 1.f);
    out[(size_t)RELOFF + (size_t)k*DD + c0] = r0/cdiv;
    out[(size_t)RELOFF + (size_t)k*DD + c1] = r1/cdiv;
  }
}

extern "C" void kernel_launch(void* const* d_in, const int* in_sizes, int n_in,
                              void* d_out, int out_size, void* d_ws, size_t ws_size,
                              hipStream_t stream) {
  (void)in_sizes; (void)n_in; (void)ws_size; (void)out_size;
  const int*   trip = (const int*)  d_in[0];
  const float* ent  = (const float*)d_in[1];
  const float* rel  = (const float*)d_in[2];
  const float* aw   = (const float*)d_in[3];
  const float* ab   = (const float*)d_in[4];
  const float* a2w  = (const float*)d_in[5];
  const float* a2b  = (const float*)d_in[6];
  const float* bn0g = (const float*)d_in[7];
  const float* bn0b = (const float*)d_in[8];
  const float* bn1g = (const float*)d_in[9];
  const float* bn1b = (const float*)d_in[10];
  float* out = (float*)d_out;
  // Xbf scratch lives in the entity half of d_out (overwritten later by k_gent)
  unsigned short* Xbf = (unsigned short*)d_out;

  char* w = (char*)d_ws;
  size_t off = 0;
  auto take = [&](size_t bytes) -> char* {
    char* p = w + off;
    off = (off + bytes + 511) & ~(size_t)511;
    return p;
  };
  // zeroed region (accumulators)
  float* S        = (float*)take(512);
  float* Q        = (float*)take(512);
  float* colsum   = (float*)take(512);
  float* colsumsq = (float*)take(512);
  int*   cnt      = (int*)  take((size_t)NE*4);
  size_t zero_end = off;
  // non-zeroed (fully overwritten each launch)
  int*   cntR   = (int*)  take((size_t)NR*4);
  float* alpha0 = (float*)take(512);
  float* alpha1 = (float*)take(512);
  float* alpha2 = (float*)take(512);
  float* beta0  = (float*)take(512);
  float* beta1  = (float*)take(512);
  float* biasv  = (float*)take(512);
  float* A1     = (float*)take(512);
  float* B1     = (float*)take(512);
  float* a2A    = (float*)take(512);
  float* sbase  = (float*)take(512);
  float* rho    = (float*)take((size_t)NR*4);
  float* sig    = (float*)take((size_t)NE*2*4);
  int*   offE   = (int*)  take((size_t)(NE+1)*4);
  int*   curE   = (int*)  take((size_t)NE*4);
  int*   offR   = (int*)  take((size_t)(NR+1)*4);
  int*   gHist  = (int*)  take((size_t)NBH*NR*4);
  int*   gBase  = (int*)  take((size_t)NBH*NR*4);
  int*   bsum   = (int*)  take((size_t)NBS*4);
  unsigned long long* evE = (unsigned long long*)take((size_t)NEV*8);
  unsigned long long* evR = (unsigned long long*)take((size_t)NT*8);
  float* V      = (float*)take((size_t)NR*DD*4);
  unsigned short* Vbf = (unsigned short*)take((size_t)NR*DD*2);
  unsigned short* Wt2 = (unsigned short*)take((size_t)256*128*2);
  unsigned short* U   = (unsigned short*)take((size_t)NE*256*2);

  hipMemsetAsync(d_ws, 0, zero_end, stream);

  k_hist     <<<NBH, 256, 0, stream>>>(trip, cnt, gHist);
  k_histscan <<<1, 512, 0, stream>>>(gHist, gBase, cntR, offR);
  k_scan1    <<<NBS, 1024, 0, stream>>>(cnt, offE, bsum);
  k_scan23   <<<NBS, 1024, 0, stream>>>(bsum, offE, curE);
  k_scat_ent <<<(NT+255)/256, 256, 0, stream>>>(trip, curE, evE);
  k_scat_rel <<<NBH, 256, 0, stream>>>(trip, gBase, evR);
  k_entstats <<<(NE+127)/128, 256, 0, stream>>>(ent, cnt, S, Q, Xbf);
  k_alpha    <<<1, 128, 0, stream>>>(rel, cntR, S, Q, bn0g, bn0b, alpha0, alpha1, alpha2, beta0, beta1);
  k_fold     <<<884, 128, 0, stream>>>(aw, ab, bn0b, rel, alpha0, alpha1, alpha2, beta0, beta1,
                                       biasv, V, Vbf, Wt2);
  k_u2       <<<1563, 256, 0, stream>>>(Xbf, Wt2, U);
  k_c1b      <<<2048, 256, 0, stream>>>((const uint2*)evE, U, Vbf, biasv, colsum, colsumsq);
  k_bn1fin   <<<1, 128, 0, stream>>>(colsum, colsumsq, bn1g, bn1b, a2w, a2b, biasv, A1, B1, a2A, sbase);
  k_sigrho   <<<NE/4 + (NR+3)/4, 256, 0, stream>>>(U, V, a2A, sig, rho);
  k_gent     <<<NE/4, 256, 0, stream>>>((const uint2*)evE, offE, U, Vbf, sig, rho, biasv, A1, B1, sbase, out);
  k_grel2    <<<NR, 1024, 0, stream>>>((const uint2*)evR, offR, U, V, sig, rho, biasv, A1, B1, sbase, cntR, out);
}

// Round 15
// 348.881 us; speedup vs baseline: 1.1030x; 1.1030x over previous
//
#include <hip/hip_runtime.h>
#include <hip/hip_bf16.h>

#define NE 100000
#define NR 500
#define DD 128
#define NT 250000
#define NEV 500000             // 2*NT events
#define RELOFF 12800000        // NE*DD
#define TWO_NF 500000.0f
#define NTF 250000.0f
#define TBH 2048
#define NBH ((NT + TBH - 1)/TBH)   // 123
#define NBS ((NE + 1023)/1024)     // 98

typedef __attribute__((ext_vector_type(8))) short short8;
typedef __attribute__((ext_vector_type(4))) float f32x4;

__device__ __forceinline__ float bf2f(unsigned short u){
  unsigned int x = ((unsigned int)u) << 16;
  return __uint_as_float(x);
}
__device__ __forceinline__ float bf2f_lo(unsigned int u){ return __uint_as_float(u << 16); }
__device__ __forceinline__ float bf2f_hi(unsigned int u){ return __uint_as_float(u & 0xFFFF0000u); }
__device__ __forceinline__ unsigned short f2bf(float f){
  __hip_bfloat16 h = __float2bfloat16(f);
  return *reinterpret_cast<unsigned short*>(&h);
}
__device__ __forceinline__ void atomAddF(float* p, float v){ unsafeAtomicAdd(p, v); }
__device__ __forceinline__ float wredsum(float x){
  x += __shfl_xor(x, 1, 64);  x += __shfl_xor(x, 2, 64);  x += __shfl_xor(x, 4, 64);
  x += __shfl_xor(x, 8, 64);  x += __shfl_xor(x, 16, 64); x += __shfl_xor(x, 32, 64);
  return x;
}
__device__ __forceinline__ int wredsumi(int x){
  x += __shfl_xor(x, 1, 64);  x += __shfl_xor(x, 2, 64);  x += __shfl_xor(x, 4, 64);
  x += __shfl_xor(x, 8, 64);  x += __shfl_xor(x, 16, 64); x += __shfl_xor(x, 32, 64);
  return x;
}

// ---------------- K1: per-block rel histogram + entity counts ----------------
__global__ __launch_bounds__(256) void k_hist(const int* __restrict__ trip,
                                              int* __restrict__ cnt, int* __restrict__ gHist){
  __shared__ int h[NR];
  int t = threadIdx.x;
  for (int r = t; r < NR; r += 256) h[r] = 0;
  __syncthreads();
  int b0 = blockIdx.x*TBH, b1 = min(b0+TBH, NT);
  for (int i = b0 + t; i < b1; i += 256){
    int t0 = trip[3*i], t1 = trip[3*i+1], t2 = trip[3*i+2];
    atomicAdd(&cnt[t0], 1);
    atomicAdd(&cnt[t1], 1);
    atomicAdd(&h[t2], 1);
  }
  __syncthreads();
  for (int r = t; r < NR; r += 256) gHist[blockIdx.x*NR + r] = h[r];
}

// ---------------- K1b: column-scan hists -> per-(block,rel) base, cntR, offR ----------------
__global__ __launch_bounds__(512) void k_histscan(const int* __restrict__ gHist,
                                                  int* __restrict__ base, int* __restrict__ cntR,
                                                  int* __restrict__ offR){
  __shared__ int sm[512];
  int r = threadIdx.x;
  int s = 0;
  if (r < NR){
    for (int b = 0; b < NBH; ++b){ base[b*NR + r] = s; s += gHist[b*NR + r]; }
    cntR[r] = s;
  }
  sm[r] = (r < NR) ? s : 0;
  __syncthreads();
  for (int st = 1; st < 512; st <<= 1){
    int x = (r >= st) ? sm[r-st] : 0;
    __syncthreads();
    sm[r] += x;
    __syncthreads();
  }
  if (r < NR){
    int off = sm[r] - s;               // exclusive
    offR[r] = off;
    for (int b = 0; b < NBH; ++b) base[b*NR + r] += off;
  }
  if (r == 0) offR[NR] = NT;
}

// ---------------- device-wide entity scan: phase 1 (block-local) ----------------
__global__ __launch_bounds__(1024) void k_scan1(const int* __restrict__ cnt,
                                                int* __restrict__ off, int* __restrict__ bsum){
  __shared__ int wsum[16];
  int t = threadIdx.x, lane = t & 63, w = t >> 6;
  int i = blockIdx.x*1024 + t;
  int v = (i < NE) ? cnt[i] : 0;
  int x = v;
  #pragma unroll
  for (int s = 1; s < 64; s <<= 1){ int y = __shfl_up(x, s, 64); if (lane >= s) x += y; }
  if (lane == 63) wsum[w] = x;
  __syncthreads();
  if (w == 0 && lane < 16){
    int xs = wsum[lane];
    #pragma unroll
    for (int s = 1; s < 16; s <<= 1){ int y = __shfl_up(xs, s, 16); if ((lane & 15) >= s) xs += y; }
    wsum[lane] = xs;
  }
  __syncthreads();
  int wprev = (w == 0) ? 0 : wsum[w-1];
  int incl = wprev + x;
  if (i < NE) off[i] = incl - v;          // block-local exclusive
  if (t == 1023) bsum[blockIdx.x] = incl; // block total
}

// ---------------- scan phases 2+3 fused ----------------
__global__ __launch_bounds__(1024) void k_scan23(const int* __restrict__ bsum,
                                                 int* __restrict__ off, int* __restrict__ cur){
  __shared__ int basesh;
  int t = threadIdx.x;
  if (t < 64){
    int acc = 0;
    for (int b = t; b < blockIdx.x; b += 64) acc += bsum[b];
    acc = wredsumi(acc);
    if (t == 0) basesh = acc;
  }
  __syncthreads();
  int base = basesh;
  int i = blockIdx.x*1024 + t;
  if (i < NE){
    int o = off[i] + base;
    off[i] = o;
    cur[i] = o;
  }
  if (blockIdx.x == NBS-1 && t == 0) off[NE] = base + bsum[NBS-1];
}

// ---------------- scatter entity events (global cursors, nt stores) ----------------
__global__ void k_scat_ent(const int* __restrict__ trip, int* __restrict__ curE,
                           unsigned long long* __restrict__ evE){
  int i = blockIdx.x*blockDim.x + threadIdx.x;
  if (i < NT){
    int t0 = trip[3*i+0], t1 = trip[3*i+1], t2 = trip[3*i+2];
    int p0 = atomicAdd(&curE[t0], 1);
    unsigned long long e0 = (unsigned)t0 |
      ((unsigned long long)(((unsigned)t1 << 10) | ((unsigned)t2 << 1)) << 32);
    __builtin_nontemporal_store(e0, &evE[p0]);
    int p1 = atomicAdd(&curE[t1], 1);
    unsigned long long e1 = (unsigned)t1 |
      ((unsigned long long)(((unsigned)t0 << 10) | ((unsigned)t2 << 1) | 1u) << 32);
    __builtin_nontemporal_store(e1, &evE[p1]);
  }
}

// ---------------- scatter rel events (LDS cursors, deterministic bases) ----------------
__global__ __launch_bounds__(256) void k_scat_rel(const int* __restrict__ trip,
                                                  const int* __restrict__ base,
                                                  unsigned long long* __restrict__ evR){
  __shared__ int cur[NR];
  int t = threadIdx.x;
  for (int r = t; r < NR; r += 256) cur[r] = base[blockIdx.x*NR + r];
  __syncthreads();
  int b0 = blockIdx.x*TBH, b1 = min(b0+TBH, NT);
  for (int i = b0 + t; i < b1; i += 256){
    int t0 = trip[3*i], t1 = trip[3*i+1], t2 = trip[3*i+2];
    int p = atomicAdd(&cur[t2], 1);
    unsigned long long e = (unsigned)t0 | ((unsigned long long)(unsigned)t1 << 32);
    __builtin_nontemporal_store(e, &evR[p]);
  }
}

// ---------------- K2: entity column stats + fused X->bf16 convert ----------------
__global__ __launch_bounds__(256) void k_entstats(const float* __restrict__ ent, const int* __restrict__ cnt,
                                                  float* __restrict__ S, float* __restrict__ Q,
                                                  unsigned short* __restrict__ Xbf){
  int j = threadIdx.x & 127;
  int half = threadIdx.x >> 7;
  int r0 = blockIdx.x*128 + half;
  int r1 = min(blockIdx.x*128 + 128, NE);
  float s = 0.f, q = 0.f;
  for (int r = r0; r < r1; r += 2){
    float x = ent[(size_t)r*DD + j];
    Xbf[(size_t)r*DD + j] = f2bf(x);
    int w = cnt[r];
    if (w){
      float wf = (float)w;
      s += wf*x; q += wf*x*x;
    }
  }
  __shared__ float ss[256], qq[256];
  ss[threadIdx.x] = s; qq[threadIdx.x] = q; __syncthreads();
  if (half == 0){
    atomAddF(&S[j], ss[j] + ss[j+128]);
    atomAddF(&Q[j], qq[j] + qq[j+128]);
  }
}

// ---------------- K3: BN0 fold + rel variance ----------------
__global__ void k_alpha(const float* __restrict__ rel, const int* __restrict__ cntR,
                        const float* __restrict__ S, const float* __restrict__ Q,
                        const float* __restrict__ bn0g, const float* __restrict__ bn0b,
                        float* __restrict__ alpha0, float* __restrict__ alpha1, float* __restrict__ alpha2,
                        float* __restrict__ beta0, float* __restrict__ beta1){
  int j = threadIdx.x;
  float qr = 0.f;
  for (int k = 0; k < NR; ++k){
    float w = (float)cntR[k];
    float x = rel[k*DD + j];
    qr += w*x*x;
  }
  float mean = S[j] / TWO_NF;
  float var  = Q[j] / TWO_NF - mean*mean;
  float inv  = rsqrtf(var + 1e-5f);
  float a0 = inv * bn0g[j];
  float a1 = inv * bn0g[128+j];
  alpha0[j] = a0; alpha1[j] = a1;
  beta0[j] = bn0b[j]     - mean*a0;
  beta1[j] = bn0b[128+j] - mean*a1;
  float varR = qr / NTF;
  alpha2[j] = rsqrtf(varR + 1e-5f) * bn0g[256+j];
}

// ---------------- K_fold: bias (blocks 0..127) | V+Vbf (128..627) | Wt2 (628..883) ----------------
__global__ __launch_bounds__(128) void k_fold(const float* __restrict__ aw, const float* __restrict__ ab,
                        const float* __restrict__ bn0b, const float* __restrict__ rel,
                        const float* __restrict__ alpha0, const float* __restrict__ alpha1,
                        const float* __restrict__ alpha2,
                        const float* __restrict__ beta0, const float* __restrict__ beta1,
                        float* __restrict__ bias, float* __restrict__ V,
                        unsigned short* __restrict__ Vbf, unsigned short* __restrict__ Wt2){
  __shared__ float sm[128];
  int b = blockIdx.x, j = threadIdx.x;
  if (b < 128){
    int o = b;
    const float* r = aw + (size_t)o*384;
    float p = r[j]*beta0[j] + r[128+j]*beta1[j] + r[256+j]*bn0b[256+j];
    sm[j] = p; __syncthreads();
    for (int s = 64; s > 0; s >>= 1){ if (j < s) sm[j] += sm[j+s]; __syncthreads(); }
    if (j == 0) bias[o] = ab[o] + sm[0];
  } else if (b < 628){
    int k = b - 128;
    sm[j] = rel[k*DD + j] * alpha2[j];
    __syncthreads();
    float acc = 0.f;
    #pragma unroll 8
    for (int q = 0; q < 128; ++q) acc += aw[(size_t)j*384 + 256 + q] * sm[q];
    V[k*DD + j] = acc;
    Vbf[k*DD + j] = f2bf(acc);
  } else {
    int o = b - 628;           // 0..255
    int k = j;                 // 0..127
    float w;
    if (o < 128) w = aw[(size_t)o*384 + k] * alpha0[k];
    else         w = aw[(size_t)(o-128)*384 + 128 + k] * alpha1[k];
    Wt2[(size_t)o*128 + k] = f2bf(w);
  }
}

// ---------------- K6: U table via MFMA — wave owns 4 output tiles, B in registers ----------------
__global__ __launch_bounds__(256) void k_u2(const unsigned short* __restrict__ Xbf,
                                            const unsigned short* __restrict__ Wt2,
                                            unsigned short* __restrict__ Uo){
  int tid = threadIdx.x;
  int w = tid >> 6, l = tid & 63;
  int col = l & 15, grp = l >> 4, kof = grp*8;
  int e0 = blockIdx.x*64;                    // 1563 blocks * 64 = 100032
  int ot0 = w*4;

  const unsigned short* wb0 = Wt2 + (size_t)((ot0+0)*16 + col)*128 + kof;
  const unsigned short* wb1 = Wt2 + (size_t)((ot0+1)*16 + col)*128 + kof;
  const unsigned short* wb2 = Wt2 + (size_t)((ot0+2)*16 + col)*128 + kof;
  const unsigned short* wb3 = Wt2 + (size_t)((ot0+3)*16 + col)*128 + kof;
  short8 b00 = *(const short8*)(wb0);
  short8 b01 = *(const short8*)(wb0+32);
  short8 b02 = *(const short8*)(wb0+64);
  short8 b03 = *(const short8*)(wb0+96);
  short8 b10 = *(const short8*)(wb1);
  short8 b11 = *(const short8*)(wb1+32);
  short8 b12 = *(const short8*)(wb1+64);
  short8 b13 = *(const short8*)(wb1+96);
  short8 b20 = *(const short8*)(wb2);
  short8 b21 = *(const short8*)(wb2+32);
  short8 b22 = *(const short8*)(wb2+64);
  short8 b23 = *(const short8*)(wb2+96);
  short8 b30 = *(const short8*)(wb3);
  short8 b31 = *(const short8*)(wb3+32);
  short8 b32 = *(const short8*)(wb3+64);
  short8 b33 = *(const short8*)(wb3+96);

  #pragma unroll
  for (int et = 0; et < 4; ++et){
    int ebase = e0 + et*16;
    int e = min(ebase + col, NE-1);
    const unsigned short* xrow = Xbf + (size_t)e*DD;
    short8 a0 = *(const short8*)(xrow + kof);
    short8 a1 = *(const short8*)(xrow + 32 + kof);
    short8 a2 = *(const short8*)(xrow + 64 + kof);
    short8 a3 = *(const short8*)(xrow + 96 + kof);
    f32x4 c0 = (f32x4){0.f,0.f,0.f,0.f};
    f32x4 c1 = (f32x4){0.f,0.f,0.f,0.f};
    f32x4 c2 = (f32x4){0.f,0.f,0.f,0.f};
    f32x4 c3 = (f32x4){0.f,0.f,0.f,0.f};
    c0 = __builtin_amdgcn_mfma_f32_16x16x32_bf16(a0, b00, c0, 0, 0, 0);
    c1 = __builtin_amdgcn_mfma_f32_16x16x32_bf16(a0, b10, c1, 0, 0, 0);
    c2 = __builtin_amdgcn_mfma_f32_16x16x32_bf16(a0, b20, c2, 0, 0, 0);
    c3 = __builtin_amdgcn_mfma_f32_16x16x32_bf16(a0, b30, c3, 0, 0, 0);
    c0 = __builtin_amdgcn_mfma_f32_16x16x32_bf16(a1, b01, c0, 0, 0, 0);
    c1 = __builtin_amdgcn_mfma_f32_16x16x32_bf16(a1, b11, c1, 0, 0, 0);
    c2 = __builtin_amdgcn_mfma_f32_16x16x32_bf16(a1, b21, c2, 0, 0, 0);
    c3 = __builtin_amdgcn_mfma_f32_16x16x32_bf16(a1, b31, c3, 0, 0, 0);
    c0 = __builtin_amdgcn_mfma_f32_16x16x32_bf16(a2, b02, c0, 0, 0, 0);
    c1 = __builtin_amdgcn_mfma_f32_16x16x32_bf16(a2, b12, c1, 0, 0, 0);
    c2 = __builtin_amdgcn_mfma_f32_16x16x32_bf16(a2, b22, c2, 0, 0, 0);
    c3 = __builtin_amdgcn_mfma_f32_16x16x32_bf16(a2, b32, c3, 0, 0, 0);
    c0 = __builtin_amdgcn_mfma_f32_16x16x32_bf16(a3, b03, c0, 0, 0, 0);
    c1 = __builtin_amdgcn_mfma_f32_16x16x32_bf16(a3, b13, c1, 0, 0, 0);
    c2 = __builtin_amdgcn_mfma_f32_16x16x32_bf16(a3, b23, c2, 0, 0, 0);
    c3 = __builtin_amdgcn_mfma_f32_16x16x32_bf16(a3, b33, c3, 0, 0, 0);
    #pragma unroll
    for (int r = 0; r < 4; ++r){
      int row = ebase + 4*grp + r;
      if (row < NE){
        size_t rb = (size_t)row*256 + col;
        Uo[rb + (ot0+0)*16] = f2bf(c0[r]);
        Uo[rb + (ot0+1)*16] = f2bf(c1[r]);
        Uo[rb + (ot0+2)*16] = f2bf(c2[r]);
        Uo[rb + (ot0+3)*16] = f2bf(c3[r]);
      }
    }
  }
}

// ---------------- K7: BN1 column stats over CSR events (unroll x4, bf16 V) ----------------
__global__ __launch_bounds__(256) void k_c1b(const uint2* __restrict__ evE,
                   const unsigned short* __restrict__ U, const unsigned short* __restrict__ Vbf,
                   const float* __restrict__ bias,
                   float* __restrict__ colsum, float* __restrict__ colsumsq){
  int lane = threadIdx.x & 63;
  int w = threadIdx.x >> 6;
  int wv = blockIdx.x*4 + w;
  int nwv = gridDim.x*4;
  int per = (NEV + nwv - 1) / nwv;
  int st = wv*per, en = min(st + per, NEV);
  int c0 = 2*lane, c1 = c0+1;
  float b0 = bias[c0], b1 = bias[c1];
  const ushort2* Ub = (const ushort2*)U;
  const ushort2* Vb = (const ushort2*)Vbf;
  float s0=0.f, s1=0.f, q0=0.f, q1=0.f;
  for (int bs = st; bs < en; bs += 64){
    int n = min(64, en - bs);
    uint2 ev = (bs + lane < en) ? evE[bs + lane] : make_uint2(0u, 0u);
    int j = 0;
    for (; j + 4 <= n; j += 4){
      unsigned ow0 = __shfl(ev.x, j, 64),   pk0 = __shfl(ev.y, j, 64);
      unsigned ow1 = __shfl(ev.x, j+1, 64), pk1 = __shfl(ev.y, j+1, 64);
      unsigned ow2 = __shfl(ev.x, j+2, 64), pk2 = __shfl(ev.y, j+2, 64);
      unsigned ow3 = __shfl(ev.x, j+3, 64), pk3 = __shfl(ev.y, j+3, 64);
      ushort2 a0 = Ub[(size_t)ow0*128 + lane];
      ushort2 g0 = Ub[(size_t)(pk0 >> 10)*128 + 64 + lane];
      ushort2 v0 = Vb[((pk0 >> 1) & 0x1FF)*64 + lane];
      ushort2 a1 = Ub[(size_t)ow1*128 + lane];
      ushort2 g1 = Ub[(size_t)(pk1 >> 10)*128 + 64 + lane];
      ushort2 v1 = Vb[((pk1 >> 1) & 0x1FF)*64 + lane];
      ushort2 a2 = Ub[(size_t)ow2*128 + lane];
      ushort2 g2 = Ub[(size_t)(pk2 >> 10)*128 + 64 + lane];
      ushort2 v2 = Vb[((pk2 >> 1) & 0x1FF)*64 + lane];
      ushort2 a3 = Ub[(size_t)ow3*128 + lane];
      ushort2 g3 = Ub[(size_t)(pk3 >> 10)*128 + 64 + lane];
      ushort2 v3 = Vb[((pk3 >> 1) & 0x1FF)*64 + lane];
      float sg0 = (pk0 & 1) ? -1.f : 1.f;
      float sg1 = (pk1 & 1) ? -1.f : 1.f;
      float sg2 = (pk2 & 1) ? -1.f : 1.f;
      float sg3 = (pk3 & 1) ? -1.f : 1.f;
      float y00 = bf2f(a0.x) + bf2f(g0.x) + sg0*bf2f(v0.x) + b0;
      float y01 = bf2f(a0.y) + bf2f(g0.y) + sg0*bf2f(v0.y) + b1;
      float y10 = bf2f(a1.x) + bf2f(g1.x) + sg1*bf2f(v1.x) + b0;
      float y11 = bf2f(a1.y) + bf2f(g1.y) + sg1*bf2f(v1.y) + b1;
      float y20 = bf2f(a2.x) + bf2f(g2.x) + sg2*bf2f(v2.x) + b0;
      float y21 = bf2f(a2.y) + bf2f(g2.y) + sg2*bf2f(v2.y) + b1;
      float y30 = bf2f(a3.x) + bf2f(g3.x) + sg3*bf2f(v3.x) + b0;
      float y31 = bf2f(a3.y) + bf2f(g3.y) + sg3*bf2f(v3.y) + b1;
      s0 += y00 + y10 + y20 + y30;
      s1 += y01 + y11 + y21 + y31;
      q0 += y00*y00 + y10*y10 + y20*y20 + y30*y30;
      q1 += y01*y01 + y11*y11 + y21*y21 + y31*y31;
    }
    for (; j < n; ++j){
      unsigned ow0 = __shfl(ev.x, j, 64), pk0 = __shfl(ev.y, j, 64);
      ushort2 a0 = Ub[(size_t)ow0*128 + lane];
      ushort2 g0 = Ub[(size_t)(pk0 >> 10)*128 + 64 + lane];
      ushort2 v0 = Vb[((pk0 >> 1) & 0x1FF)*64 + lane];
      float sg0 = (pk0 & 1) ? -1.f : 1.f;
      float y00 = bf2f(a0.x) + bf2f(g0.x) + sg0*bf2f(v0.x) + b0;
      float y01 = bf2f(a0.y) + bf2f(g0.y) + sg0*bf2f(v0.y) + b1;
      s0 += y00;  q0 += y00*y00;
      s1 += y01;  q1 += y01*y01;
    }
  }
  __shared__ float sred[4][128], qred[4][128];
  sred[w][c0] = s0; sred[w][c1] = s1;
  qred[w][c0] = q0; qred[w][c1] = q1;
  __syncthreads();
  int t = threadIdx.x;
  if (t < 128){
    atomAddF(&colsum[t],   sred[0][t] + sred[1][t] + sred[2][t] + sred[3][t]);
    atomAddF(&colsumsq[t], qred[0][t] + qred[1][t] + qred[2][t] + qred[3][t]);
  }
}

// ---------------- K8: BN1 fold + a2 fold + pbsb ----------------
__global__ void k_bn1fin(const float* __restrict__ colsum, const float* __restrict__ colsumsq,
                         const float* __restrict__ bn1g, const float* __restrict__ bn1b,
                         const float* __restrict__ a2w, const float* __restrict__ a2b,
                         const float* __restrict__ biasv,
                         float* __restrict__ A1, float* __restrict__ B1,
                         float* __restrict__ a2A, float* __restrict__ sbase){
  int j = threadIdx.x;
  float mean = colsum[j] / TWO_NF;
  float var  = colsumsq[j] / TWO_NF - mean*mean;
  float A = rsqrtf(var + 1e-5f) * bn1g[j];
  float B = bn1b[j] - mean*A;
  A1[j] = A; B1[j] = B;
  float w2 = a2w[j];
  float aA = w2*A;
  a2A[j] = aA;
  __shared__ float sm[128], sm2[128];
  sm[j] = w2*B; sm2[j] = biasv[j]*aA;
  __syncthreads();
  for (int s = 64; s > 0; s >>= 1){
    if (j < s){ sm[j] += sm[j+s]; sm2[j] += sm2[j+s]; }
    __syncthreads();
  }
  if (j == 0){
    float sb = a2b[0] + sm[0];
    sbase[0] = sb;
    sbase[1] = sb + sm2[0];   // pbsb = dot(bias,a2A) + sbase
  }
}

// ---------------- K_sigrho: sigma (blocks 0..24999) | rho (25000..25124) ----------------
__global__ __launch_bounds__(256) void k_sigrho(const unsigned short* __restrict__ U,
                                                const float* __restrict__ V,
                                                const float* __restrict__ a2A,
                                                float* __restrict__ sig, float* __restrict__ rho){
  int lane = threadIdx.x & 63;
  if (blockIdx.x < NE/4){
    int e = blockIdx.x*4 + (threadIdx.x>>6);
    const uint2* Ur = (const uint2*)U;
    uint2 r = Ur[(size_t)e*64 + lane];
    int c = (lane & 31)*4;
    float4 w = *(const float4*)&a2A[c];
    float p = bf2f_lo(r.x)*w.x + bf2f_hi(r.x)*w.y + bf2f_lo(r.y)*w.z + bf2f_hi(r.y)*w.w;
    p += __shfl_xor(p, 1, 64); p += __shfl_xor(p, 2, 64); p += __shfl_xor(p, 4, 64);
    p += __shfl_xor(p, 8, 64); p += __shfl_xor(p, 16, 64);
    if ((lane & 31) == 0) sig[2*e + (lane >> 5)] = p;
  } else {
    int k = (blockIdx.x - NE/4)*4 + (threadIdx.x>>6);
    if (k >= NR) return;
    const float2* Vp = (const float2*)V;
    float2 v = Vp[(size_t)k*64 + lane];
    int c0 = 2*lane;
    float p = v.x*a2A[c0] + v.y*a2A[c0+1];
    p = wredsum(p);
    if (lane == 0) rho[k] = p;
  }
}

// ---------------- K9: entity gather (unroll x4, bf16 V) ----------------
__global__ __launch_bounds__(256) void k_gent(const uint2* __restrict__ evE, const int* __restrict__ offE,
                   const unsigned short* __restrict__ U, const unsigned short* __restrict__ Vbf,
                   const float* __restrict__ sig, const float* __restrict__ rho,
                   const float* __restrict__ bias,
                   const float* __restrict__ A1, const float* __restrict__ B1,
                   const float* __restrict__ sbase,
                   float* __restrict__ out){
  int lane = threadIdx.x & 63;
  int e = blockIdx.x*4 + (threadIdx.x>>6);
  if (e >= NE) return;
  int c0 = 2*lane, c1 = c0+1;
  const ushort2* Ub = (const ushort2*)U;
  const ushort2* Vb = (const ushort2*)Vbf;
  ushort2 u0 = Ub[(size_t)e*128 + lane];
  float base0 = bf2f(u0.x) + bias[c0], base1 = bf2f(u0.y) + bias[c1];
  float pb  = sbase[1];
  float s0e = sig[2*e];
  float accU0=0.f, accU1=0.f, accV0=0.f, accV1=0.f, sep=0.f;
  int p0 = offE[e], p1 = offE[e+1];
  for (int bs = p0; bs < p1; bs += 64){
    int n = min(64, p1 - bs);
    unsigned ev = 0u; float ebl = 0.f;
    if (bs + lane < p1){
      ev = evE[bs + lane].y;
      int oth = ev >> 10, rl = (ev >> 1) & 0x1FF;
      float sg = (ev & 1) ? -1.f : 1.f;
      float s = s0e + sig[2*oth + 1] + sg*rho[rl] + pb;
      float bb = (s >= 0.f) ? -s : -0.01f*s;
      ebl = expf(bb);
    }
    sep += ebl;
    int j = 0;
    for (; j + 4 <= n; j += 4){
      unsigned e0 = __shfl(ev, j, 64);
      unsigned e1 = __shfl(ev, j+1, 64);
      unsigned e2 = __shfl(ev, j+2, 64);
      unsigned e3 = __shfl(ev, j+3, 64);
      float eb0 = __shfl(ebl, j, 64);
      float eb1 = __shfl(ebl, j+1, 64);
      float eb2 = __shfl(ebl, j+2, 64);
      float eb3 = __shfl(ebl, j+3, 64);
      ushort2 g0 = Ub[(size_t)(e0 >> 10)*128 + 64 + lane];
      ushort2 g1 = Ub[(size_t)(e1 >> 10)*128 + 64 + lane];
      ushort2 g2 = Ub[(size_t)(e2 >> 10)*128 + 64 + lane];
      ushort2 g3 = Ub[(size_t)(e3 >> 10)*128 + 64 + lane];
      ushort2 v0 = Vb[((e0 >> 1) & 0x1FF)*64 + lane];
      ushort2 v1 = Vb[((e1 >> 1) & 0x1FF)*64 + lane];
      ushort2 v2 = Vb[((e2 >> 1) & 0x1FF)*64 + lane];
      ushort2 v3 = Vb[((e3 >> 1) & 0x1FF)*64 + lane];
      float w0 = (e0 & 1) ? -eb0 : eb0;
      float w1 = (e1 & 1) ? -eb1 : eb1;
      float w2 = (e2 & 1) ? -eb2 : eb2;
      float w3 = (e3 & 1) ? -eb3 : eb3;
      accU0 += eb0*bf2f(g0.x); accU1 += eb0*bf2f(g0.y);
      accV0 += w0*bf2f(v0.x);  accV1 += w0*bf2f(v0.y);
      accU0 += eb1*bf2f(g1.x); accU1 += eb1*bf2f(g1.y);
      accV0 += w1*bf2f(v1.x);  accV1 += w1*bf2f(v1.y);
      accU0 += eb2*bf2f(g2.x); accU1 += eb2*bf2f(g2.y);
      accV0 += w2*bf2f(v2.x);  accV1 += w2*bf2f(v2.y);
      accU0 += eb3*bf2f(g3.x); accU1 += eb3*bf2f(g3.y);
      accV0 += w3*bf2f(v3.x);  accV1 += w3*bf2f(v3.y);
    }
    for (; j < n; ++j){
      unsigned e0 = __shfl(ev, j, 64);
      float eb0 = __shfl(ebl, j, 64);
      ushort2 g0 = Ub[(size_t)(e0 >> 10)*128 + 64 + lane];
      ushort2 v0 = Vb[((e0 >> 1) & 0x1FF)*64 + lane];
      float w0 = (e0 & 1) ? -eb0 : eb0;
      accU0 += eb0*bf2f(g0.x); accU1 += eb0*bf2f(g0.y);
      accV0 += w0*bf2f(v0.x);  accV1 += w0*bf2f(v0.y);
    }
  }
  float se = wredsum(sep);
  float sY0 = se*base0 + accU0 + accV0;
  float sY1 = se*base1 + accU1 + accV1;
  float hs0 = A1[c0]*sY0 + B1[c0]*se;
  float hs1 = A1[c1]*sY1 + B1[c1]*se;
  float d = (se == 0.f) ? 1e-12f : se;
  out[(size_t)e*DD + c0] = hs0/d;
  out[(size_t)e*DD + c1] = hs1/d;
}

// ---------------- K10: relation gather — one block (16 waves) per rel, direct write ----------------
__global__ __launch_bounds__(1024) void k_grel2(const uint2* __restrict__ evR, const int* __restrict__ offR,
                   const unsigned short* __restrict__ U, const float* __restrict__ V,
                   const float* __restrict__ sig, const float* __restrict__ rho,
                   const float* __restrict__ bias,
                   const float* __restrict__ A1, const float* __restrict__ B1,
                   const float* __restrict__ sbase, const int* __restrict__ cntR,
                   float* __restrict__ out){
  __shared__ float rA[16][64], rB[16][64], sepw[16];
  int lane = threadIdx.x & 63;
  int w = threadIdx.x >> 6;       // 0..15
  int k = blockIdx.x;
  int c0 = 2*lane, c1 = c0+1;
  const ushort2* Ub = (const ushort2*)U;
  const float2*  Vp = (const float2*)V;
  float2 v = Vp[(size_t)k*64 + lane];
  float vb0 = v.x + bias[c0], vb1 = v.y + bias[c1];
  float rpb = rho[k] + sbase[1];
  float accY0=0.f, accY1=0.f, sep=0.f;
  int p0 = offR[k], p1 = offR[k+1];
  for (int bs = p0 + w*64; bs < p1; bs += 16*64){
    int n = min(64, p1 - bs);
    uint2 ev = make_uint2(0u, 0u); float ebl = 0.f;
    if (bs + lane < p1){
      ev = evR[bs + lane];
      float s = sig[2*ev.x] + sig[2*ev.y + 1] + rpb;
      float bb = (s >= 0.f) ? -s : -0.01f*s;
      ebl = expf(bb);
    }
    sep += ebl;
    int j = 0;
    for (; j + 2 <= n; j += 2){
      unsigned a0 = __shfl(ev.x, j, 64),   d0 = __shfl(ev.y, j, 64);
      unsigned a1 = __shfl(ev.x, j+1, 64), d1 = __shfl(ev.y, j+1, 64);
      float eb0 = __shfl(ebl, j, 64);
      float eb1 = __shfl(ebl, j+1, 64);
      ushort2 ua0 = Ub[(size_t)a0*128 + lane];
      ushort2 ud0 = Ub[(size_t)d0*128 + 64 + lane];
      ushort2 ua1 = Ub[(size_t)a1*128 + lane];
      ushort2 ud1 = Ub[(size_t)d1*128 + 64 + lane];
      accY0 += eb0*(bf2f(ua0.x) + bf2f(ud0.x));
      accY1 += eb0*(bf2f(ua0.y) + bf2f(ud0.y));
      accY0 += eb1*(bf2f(ua1.x) + bf2f(ud1.x));
      accY1 += eb1*(bf2f(ua1.y) + bf2f(ud1.y));
    }
    for (; j < n; ++j){
      unsigned a0 = __shfl(ev.x, j, 64), d0 = __shfl(ev.y, j, 64);
      float eb0 = __shfl(ebl, j, 64);
      ushort2 ua0 = Ub[(size_t)a0*128 + lane];
      ushort2 ud0 = Ub[(size_t)d0*128 + 64 + lane];
      accY0 += eb0*(bf2f(ua0.x) + bf2f(ud0.x));
      accY1 += eb0*(bf2f(ua0.y) + bf2f(ud0.y));
    }
  }
  float se_w = wredsum(sep);
  rA[w][lane] = accY0;
  rB[w][lane] = accY1;
  if (lane == 0) sepw[w] = se_w;
  __syncthreads();
  if (threadIdx.x < 64){
    int l = threadIdx.x;
    float sY0 = 0.f, sY1 = 0.f, se = 0.f;
    #pragma unroll
    for (int ww = 0; ww < 16; ++ww){ sY0 += rA[ww][l]; sY1 += rB[ww][l]; se += sepw[ww]; }
    sY0 += se*vb0;
    sY1 += se*vb1;
    float r0 = A1[c0]*sY0 + B1[c0]*se;
    float r1 = A1[c1]*sY1 + B1[c1]*se;
    float cdiv = fmaxf((float)cntR[k], 1.f);
    out[(size_t)RELOFF + (size_t)k*DD + c0] = r0/cdiv;
    out[(size_t)RELOFF + (size_t)k*DD + c1] = r1/cdiv;
  }
}

extern "C" void kernel_launch(void* const* d_in, const int* in_sizes, int n_in,
                              void* d_out, int out_size, void* d_ws, size_t ws_size,
                              hipStream_t stream) {
  (void)in_sizes; (void)n_in; (void)ws_size; (void)out_size;
  const int*   trip = (const int*)  d_in[0];
  const float* ent  = (const float*)d_in[1];
  const float* rel  = (const float*)d_in[2];
  const float* aw   = (const float*)d_in[3];
  const float* ab   = (const float*)d_in[4];
  const float* a2w  = (const float*)d_in[5];
  const float* a2b  = (const float*)d_in[6];
  const float* bn0g = (const float*)d_in[7];
  const float* bn0b = (const float*)d_in[8];
  const float* bn1g = (const float*)d_in[9];
  const float* bn1b = (const float*)d_in[10];
  float* out = (float*)d_out;
  // Xbf scratch lives in the entity half of d_out (overwritten later by k_gent)
  unsigned short* Xbf = (unsigned short*)d_out;

  char* w = (char*)d_ws;
  size_t off = 0;
  auto take = [&](size_t bytes) -> char* {
    char* p = w + off;
    off = (off + bytes + 511) & ~(size_t)511;
    return p;
  };
  // zeroed region (accumulators)
  float* S        = (float*)take(512);
  float* Q        = (float*)take(512);
  float* colsum   = (float*)take(512);
  float* colsumsq = (float*)take(512);
  int*   cnt      = (int*)  take((size_t)NE*4);
  size_t zero_end = off;
  // non-zeroed (fully overwritten each launch)
  int*   cntR   = (int*)  take((size_t)NR*4);
  float* alpha0 = (float*)take(512);
  float* alpha1 = (float*)take(512);
  float* alpha2 = (float*)take(512);
  float* beta0  = (float*)take(512);
  float* beta1  = (float*)take(512);
  float* biasv  = (float*)take(512);
  float* A1     = (float*)take(512);
  float* B1     = (float*)take(512);
  float* a2A    = (float*)take(512);
  float* sbase  = (float*)take(512);
  float* rho    = (float*)take((size_t)NR*4);
  float* sig    = (float*)take((size_t)NE*2*4);
  int*   offE   = (int*)  take((size_t)(NE+1)*4);
  int*   curE   = (int*)  take((size_t)NE*4);
  int*   offR   = (int*)  take((size_t)(NR+1)*4);
  int*   gHist  = (int*)  take((size_t)NBH*NR*4);
  int*   gBase  = (int*)  take((size_t)NBH*NR*4);
  int*   bsum   = (int*)  take((size_t)NBS*4);
  unsigned long long* evE = (unsigned long long*)take((size_t)NEV*8);
  unsigned long long* evR = (unsigned long long*)take((size_t)NT*8);
  float* V      = (float*)take((size_t)NR*DD*4);
  unsigned short* Vbf = (unsigned short*)take((size_t)NR*DD*2);
  unsigned short* Wt2 = (unsigned short*)take((size_t)256*128*2);
  unsigned short* U   = (unsigned short*)take((size_t)NE*256*2);

  hipMemsetAsync(d_ws, 0, zero_end, stream);

  k_hist     <<<NBH, 256, 0, stream>>>(trip, cnt, gHist);
  k_histscan <<<1, 512, 0, stream>>>(gHist, gBase, cntR, offR);
  k_scan1    <<<NBS, 1024, 0, stream>>>(cnt, offE, bsum);
  k_scan23   <<<NBS, 1024, 0, stream>>>(bsum, offE, curE);
  k_scat_ent <<<(NT+255)/256, 256, 0, stream>>>(trip, curE, evE);
  k_scat_rel <<<NBH, 256, 0, stream>>>(trip, gBase, evR);
  k_entstats <<<(NE+127)/128, 256, 0, stream>>>(ent, cnt, S, Q, Xbf);
  k_alpha    <<<1, 128, 0, stream>>>(rel, cntR, S, Q, bn0g, bn0b, alpha0, alpha1, alpha2, beta0, beta1);
  k_fold     <<<884, 128, 0, stream>>>(aw, ab, bn0b, rel, alpha0, alpha1, alpha2, beta0, beta1,
                                       biasv, V, Vbf, Wt2);
  k_u2       <<<1563, 256, 0, stream>>>(Xbf, Wt2, U);
  k_c1b      <<<2048, 256, 0, stream>>>((const uint2*)evE, U, Vbf, biasv, colsum, colsumsq);
  k_bn1fin   <<<1, 128, 0, stream>>>(colsum, colsumsq, bn1g, bn1b, a2w, a2b, biasv, A1, B1, a2A, sbase);
  k_sigrho   <<<NE/4 + (NR+3)/4, 256, 0, stream>>>(U, V, a2A, sig, rho);
  k_gent     <<<NE/4, 256, 0, stream>>>((const uint2*)evE, offE, U, Vbf, sig, rho, biasv, A1, B1, sbase, out);
  k_grel2    <<<NR, 1024, 0, stream>>>((const uint2*)evR, offR, U, V, sig, rho, biasv, A1, B1, sbase, cntR, out);
}